// Round 10
// baseline (289.752 us; speedup 1.0000x reference)
//
#include <hip/hip_runtime.h>
#include <math.h>

#define BB 16
#define NN 25200
#define NCLS 80
#define TOPK 1000
#define MAXDET 100
#define TIE_CAP 4096
#define CAND_CAP 1024
#define BPI_C 99    // blocks/img for k_compact: ceil(25200/256)
#define BPI_S 394   // blocks/img for k_score:  ceil(25200*4/256)
static constexpr float NEGV = -1000000000.0f;
static constexpr float IMGSZ = 640.0f;

struct Meta {
  unsigned b1;
  unsigned c_gt;
  unsigned cnt;
  unsigned tie_cnt;
};

__device__ __forceinline__ unsigned flipKey(float f) {
  unsigned u = __float_as_uint(f);
  return (u & 0x80000000u) ? ~u : (u | 0x80000000u);
}
__device__ __forceinline__ float unflipKey(unsigned k) {
  unsigned u = (k & 0x80000000u) ? (k & 0x7FFFFFFFu) : ~k;
  return __uint_as_float(u);
}

// 32-bit unsigned max DPP step (bound_ctrl=1 -> invalid lanes read 0 = identity)
#define UMAX_DPP(VAR, CTRL)                                                                   \
  {                                                                                           \
    unsigned _o = (unsigned)__builtin_amdgcn_update_dpp(0, (int)(VAR), CTRL, 0xF, 0xF, true); \
    if (_o > (VAR)) (VAR) = _o;                                                               \
  }

// (hi,lo) 64-bit-ordered max DPP step
#define U64MAX_DPP(H, L, CTRL)                                                                 \
  {                                                                                            \
    unsigned _oh = (unsigned)__builtin_amdgcn_update_dpp(0, (int)(H), CTRL, 0xF, 0xF, true);   \
    unsigned _ol = (unsigned)__builtin_amdgcn_update_dpp(0, (int)(L), CTRL, 0xF, 0xF, true);   \
    bool _g = (_oh > (H)) || ((_oh == (H)) && (_ol > (L)));                                    \
    (H) = _g ? _oh : (H);                                                                      \
    (L) = _g ? _ol : (L);                                                                      \
  }

// ---------------- phase 1: scores + high-16 histogram (4 lanes per row) ----------------
__global__ void __launch_bounds__(256) k_score(const float* __restrict__ regs,
                                               const float* __restrict__ clses,
                                               unsigned* __restrict__ keys,
                                               float* __restrict__ ccs,
                                               int* __restrict__ preds,
                                               unsigned* __restrict__ hist1) {
  int img = blockIdx.x / BPI_S;
  int t = (blockIdx.x % BPI_S) * 256 + threadIdx.x;
  int rl = t >> 2, q = t & 3;
  if (rl >= NN) return;
  size_t row = (size_t)img * NN + (size_t)rl;
  const float4* r4 = reinterpret_cast<const float4*>(clses + row * NCLS);
  float best = -1.0f;
  int bi = 0;
#pragma unroll
  for (int u = 0; u < 5; ++u) {
    float4 v = r4[q + 4 * u];
    int b0 = (q + 4 * u) * 4;
    if (v.x > best) { best = v.x; bi = b0 + 0; }
    if (v.y > best) { best = v.y; bi = b0 + 1; }
    if (v.z > best) { best = v.z; bi = b0 + 2; }
    if (v.w > best) { best = v.w; bi = b0 + 3; }
  }
  unsigned vb = __float_as_uint(best);
  unsigned m = vb;
  UMAX_DPP(m, 0xB1);  // quad_perm [1,0,3,2]
  UMAX_DPP(m, 0x4E);  // quad_perm [2,3,0,1]
  unsigned t2 = (vb == m) ? (unsigned)(79 - bi) : 0u;
  UMAX_DPP(t2, 0xB1);
  UMAX_DPP(t2, 0x4E);
  if (q == 0) {
    float bestv = __uint_as_float(m);
    int bidx = 79 - (int)t2;
    float pobj = regs[row * 5 + 4];
    float sc = pobj * bestv;
    float s = (sc >= 0.05f) ? sc : NEGV;
    unsigned key = flipKey(s);
    keys[row] = key;
    ccs[row] = bestv;
    preds[row] = bidx;
    atomicAdd(&hist1[(size_t)img * 65536 + (key >> 16)], 1u);
  }
}

// ---------------- histogram scan (single level): find cutoff high-16 bin ----------------
__global__ void __launch_bounds__(256) k_scan(const unsigned* __restrict__ hist,
                                              Meta* __restrict__ meta) {
  __shared__ unsigned part[256];
  __shared__ unsigned sfx[256];
  __shared__ int s_sel;
  __shared__ unsigned s_cum;
  int img = blockIdx.x;
  int t = threadIdx.x;
  const unsigned* h = hist + (size_t)img * 65536;
  const unsigned target = (unsigned)TOPK;
  unsigned s = 0;
  const uint4* h4 = reinterpret_cast<const uint4*>(h) + (size_t)t * 64;
  for (int j = 0; j < 64; ++j) {
    uint4 v = h4[j];
    s += v.x + v.y + v.z + v.w;
  }
  part[t] = s;
  sfx[t] = s;
  __syncthreads();
  for (int d = 1; d < 256; d <<= 1) {
    unsigned v = (t + d < 256) ? sfx[t + d] : 0u;
    __syncthreads();
    sfx[t] += v;
    __syncthreads();
  }
  {
    unsigned incl = sfx[t];
    unsigned excl = incl - part[t];
    if (incl >= target && excl < target) { s_sel = t; s_cum = excl; }
  }
  __syncthreads();
  int chunk = s_sel;
  unsigned cumAbove = s_cum;
  __syncthreads();
  unsigned b = h[(size_t)chunk * 256 + t];
  part[t] = b;
  sfx[t] = b;
  __syncthreads();
  for (int d = 1; d < 256; d <<= 1) {
    unsigned v = (t + d < 256) ? sfx[t + d] : 0u;
    __syncthreads();
    sfx[t] += v;
    __syncthreads();
  }
  {
    unsigned incl = cumAbove + sfx[t];
    unsigned excl = incl - part[t];
    if (incl >= target && excl < target) {
      meta[img].b1 = (unsigned)(chunk * 256 + t);
      meta[img].c_gt = excl;
    }
  }
}

// ---------------- decode + candidate write (global) ----------------
__device__ __forceinline__ void decode_write(int img, unsigned pos, int i,
                                             const float* __restrict__ regs,
                                             const float* __restrict__ anchors,
                                             float score, float cc, int pred,
                                             float* __restrict__ cand) {
  const size_t S = (size_t)BB * CAND_CAP;
  size_t g = (size_t)img * NN + (size_t)i;
  const float* r = regs + g * 5;
  float d0 = r[0], d1 = r[1], d2 = r[2], d3 = r[3], obj = r[4];
  const float* a = anchors + (size_t)i * 4;
  float ax1 = a[0], ay1 = a[1], ax2 = a[2], ay2 = a[3];
  float aw = ax2 - ax1, ah = ay2 - ay1;
  float acx = (ax1 + ax2) * 0.5f, acy = (ay1 + ay2) * 0.5f;
  float cx = acx + d0 * aw, cy = acy + d1 * ah;
  float w = aw * expf(d2), h = ah * expf(d3);
  float hw = 0.5f * w, hh = 0.5f * h;
  float x1 = fminf(fmaxf(cx - hw, 0.0f), IMGSZ);
  float y1 = fminf(fmaxf(cy - hh, 0.0f), IMGSZ);
  float x2 = fminf(fmaxf(cx + hw, 0.0f), IMGSZ);
  float y2 = fminf(fmaxf(cy + hh, 0.0f), IMGSZ);
  size_t o = (size_t)img * CAND_CAP + pos;
  cand[0 * S + o] = x1;
  cand[1 * S + o] = y1;
  cand[2 * S + o] = x2;
  cand[3 * S + o] = y2;
  cand[4 * S + o] = obj;
  cand[5 * S + o] = cc;
  cand[6 * S + o] = (float)pred;
  cand[7 * S + o] = score;
  reinterpret_cast<unsigned*>(cand + 8 * S)[o] = (unsigned)i;
}

// ---------------- compaction: wave-aggregated atomics (1 atomic/wave) ----------------
__global__ void k_compact(const float* __restrict__ regs, const float* __restrict__ anchors,
                          const unsigned* __restrict__ keys, const float* __restrict__ ccs,
                          const int* __restrict__ preds, Meta* __restrict__ meta,
                          float* __restrict__ cand, unsigned long long* __restrict__ ties) {
  int img = blockIdx.x / BPI_C;
  int i = (blockIdx.x % BPI_C) * 256 + threadIdx.x;
  if (i >= NN) return;
  int lane = threadIdx.x & 63;
  unsigned long long lt = (1ull << lane) - 1ull;
  size_t g = (size_t)img * NN + (size_t)i;
  unsigned key = keys[g];
  unsigned k16 = key >> 16;
  unsigned b1 = meta[img].b1;

  bool above = k16 > b1;
  unsigned long long mA = __ballot(above);
  if (above) {
    int leader = __builtin_ctzll(mA);
    unsigned base = 0;
    if (lane == leader) base = atomicAdd(&meta[img].cnt, (unsigned)__popcll(mA));
    base = __shfl(base, leader);
    unsigned pos = base + (unsigned)__popcll(mA & lt);
    if (pos < CAND_CAP)
      decode_write(img, pos, i, regs, anchors, unflipKey(key), ccs[g], preds[g], cand);
  }
  bool tie = (k16 == b1);
  unsigned long long mT = __ballot(tie);
  if (tie) {
    int leader = __builtin_ctzll(mT);
    unsigned base = 0;
    if (lane == leader) base = atomicAdd(&meta[img].tie_cnt, (unsigned)__popcll(mT));
    base = __shfl(base, leader);
    unsigned tp = base + (unsigned)__popcll(mT & lt);
    if (tp < TIE_CAP)
      ties[(size_t)img * TIE_CAP + tp] =
          ((unsigned long long)key << 15) | (unsigned long long)(0x7FFFu - (unsigned)i);
  }
}

// ---------------- NMS: sort-then-scan, ONE wave per image ----------------
// Sort 1024 u64 keys (score desc, anchor idx asc; slot in low 10 bits -> unique) with a
// single-wave LDS bitonic (55 stages). Then greedy NMS = scan in sorted order:
// alive = 16 wave-uniform u64 words (scalar regs). Per iteration: scalar ffs over 16
// words -> winner rank r -> ONE uniform ds_read_b128 (boxe[r]) -> 16 per-lane in-register
// division-free IoU tests; suppression ballot (= the v_cmp itself) ANDs into alive.
// NO argmax reduce, NO cross-wave sync, NO runtime-indexed register arrays.
__global__ void __launch_bounds__(64, 1) k_nms(const float* __restrict__ cand,
                                               const Meta* __restrict__ meta,
                                               float* __restrict__ out,
                                               const float* __restrict__ regs,
                                               const float* __restrict__ anchors,
                                               const float* __restrict__ ccs,
                                               const int* __restrict__ preds,
                                               const unsigned long long* __restrict__ ties) {
  const size_t S = (size_t)BB * CAND_CAP;
  int img = blockIdx.x;
  int lane = threadIdx.x;

  __shared__ float4 boxo[CAND_CAP];             // offset boxes by slot      16 KB
  __shared__ float4 boxe[CAND_CAP];             // offset boxes by rank      16 KB
  __shared__ float4 pay0[CAND_CAP];             // x1,y1,x2,y2 by slot       16 KB
  __shared__ float4 pay1[CAND_CAP];             // obj,cc,cp,score by slot   16 KB
  __shared__ unsigned long long key64[CAND_CAP];  // sort keys                8 KB
  __shared__ unsigned wins[MAXDET];             // winner ranks             400 B
  __shared__ float4 lout4[MAXDET * 7 / 4];      // output staging          2.8 KB
  float* lout = reinterpret_cast<float*>(lout4);

  unsigned cnt = meta[img].cnt;
  unsigned c_gt = meta[img].c_gt;
  unsigned tcnt = meta[img].tie_cnt;
  if (tcnt > TIE_CAP) tcnt = TIE_CAP;
  unsigned need = (unsigned)TOPK - c_gt;
  if (need > tcnt) need = tcnt;

  // ---- (1) load candidates into LDS by slot; build key64 ----
#pragma unroll
  for (int k = 0; k < 16; ++k) {
    int c = k * 64 + lane;
    size_t o = (size_t)img * CAND_CAP + (size_t)c;
    bool v = c < (int)cnt;
    float vx1 = cand[0 * S + o], vy1 = cand[1 * S + o];
    float vx2 = cand[2 * S + o], vy2 = cand[3 * S + o];
    float vobj = cand[4 * S + o], vcc = cand[5 * S + o];
    float vcp = cand[6 * S + o], vsc = cand[7 * S + o];
    unsigned vai = reinterpret_cast<const unsigned*>(cand + 8 * S)[o];
    if (!v) { vx1 = vy1 = vx2 = vy2 = 0.f; vobj = vcc = vcp = 0.f; vsc = NEGV; vai = 0x7FFFu; }
    float offv = vcp * 4096.0f;
    boxo[c] = make_float4(vx1 + offv, vy1 + offv, vx2 + offv, vy2 + offv);
    pay0[c] = make_float4(vx1, vy1, vx2, vy2);
    pay1[c] = make_float4(vobj, vcc, vcp, vsc);
    key64[c] = v ? (((unsigned long long)flipKey(vsc) << 25) |
                    ((unsigned long long)((0x7FFFu - vai) & 0x7FFFu) << 10) |
                    (unsigned long long)c)
                 : 0ull;
  }
  if (lane < 50) { wins[lane] = 0xFFFFFFFFu; wins[lane + 50] = 0xFFFFFFFFu; }

  // ---- (2) tie rank-select: rank = #ties with bigger 62-bit key; parallel decode ----
  {
    const unsigned long long* tptr = ties + (size_t)img * TIE_CAP;
    for (unsigned base = 0; base < tcnt; base += 64) {
      unsigned p = base + (unsigned)lane;
      unsigned long long myk = (p < tcnt) ? tptr[p] : 0ull;
      unsigned rank = 0;
      for (unsigned q2 = 0; q2 < tcnt; ++q2) {
        unsigned long long other = tptr[q2];  // wave-uniform -> broadcast
        rank += (other > myk) ? 1u : 0u;
      }
      if (p < tcnt && rank < need) {
        unsigned idx = 0x7FFFu - (unsigned)(myk & 0x7FFFull);
        unsigned key32 = (unsigned)(myk >> 15);
        size_t g = (size_t)img * NN + idx;
        const float* r = regs + g * 5;
        float d0 = r[0], d1 = r[1], d2 = r[2], d3 = r[3], obj = r[4];
        const float* a = anchors + (size_t)idx * 4;
        float ax1 = a[0], ay1 = a[1], ax2 = a[2], ay2 = a[3];
        float aw = ax2 - ax1, ah = ay2 - ay1;
        float acx = (ax1 + ax2) * 0.5f, acy = (ay1 + ay2) * 0.5f;
        float cx = acx + d0 * aw, cy = acy + d1 * ah;
        float w = aw * expf(d2), h = ah * expf(d3);
        float hw = 0.5f * w, hh = 0.5f * h;
        float x1 = fminf(fmaxf(cx - hw, 0.0f), IMGSZ);
        float y1 = fminf(fmaxf(cy - hh, 0.0f), IMGSZ);
        float x2 = fminf(fmaxf(cx + hw, 0.0f), IMGSZ);
        float y2 = fminf(fmaxf(cy + hh, 0.0f), IMGSZ);
        float cc = ccs[g];
        float cp = (float)preds[g];
        float offv = cp * 4096.0f;
        int c = (int)(cnt + rank);
        boxo[c] = make_float4(x1 + offv, y1 + offv, x2 + offv, y2 + offv);
        pay0[c] = make_float4(x1, y1, x2, y2);
        pay1[c] = make_float4(obj, cc, cp, unflipKey(key32));
        key64[c] = ((unsigned long long)key32 << 25) |
                   ((unsigned long long)(0x7FFFu - idx) << 10) |
                   (unsigned long long)c;
      }
    }
  }
  __syncthreads();

  // ---- (3) single-wave LDS bitonic sort, descending (55 stages) ----
  for (unsigned len = 2; len <= CAND_CAP; len <<= 1) {
    for (unsigned inc = len >> 1; inc >= 1; inc >>= 1) {
#pragma unroll 2
      for (unsigned p = (unsigned)lane; p < CAND_CAP / 2; p += 64) {
        unsigned low = p & (inc - 1);
        unsigned i = ((p - low) << 1) + low;
        unsigned j = i + inc;
        unsigned long long a = key64[i], b = key64[j];
        bool descBlk = ((i & len) == 0);
        bool sw = descBlk ? (a < b) : (a > b);
        if (sw) { key64[i] = b; key64[j] = a; }
      }
      __syncthreads();  // single wave: waitcnt-only, cheap
    }
  }

  // ---- (4) sorted register load: rank -> slot -> box; build boxe; count valid ----
  float x1o[16], y1o[16], x2o[16], y2o[16], area[16];
  const unsigned validThr = flipKey(NEGV * 0.5f);
  unsigned nvalid = 0;
#pragma unroll
  for (int k = 0; k < 16; ++k) {
    int c = k * 64 + lane;
    unsigned long long key = key64[c];
    unsigned slot = (unsigned)(key & 1023ull);
    float4 B = boxo[slot];  // key==0 -> slot 0 junk; masked out by alive below
    boxe[c] = B;
    x1o[k] = B.x; y1o[k] = B.y; x2o[k] = B.z; y2o[k] = B.w;
    area[k] = (B.z - B.x) * (B.w - B.y);
    nvalid += (unsigned)__popcll(__ballot((unsigned)(key >> 25) > validThr));
  }
  __syncthreads();

  // alive mask: ranks [0, nvalid) — wave-uniform words (scalar regs)
  unsigned long long alive[16];
#pragma unroll
  for (int k = 0; k < 16; ++k) {
    int lo = k * 64;
    alive[k] = (nvalid >= (unsigned)(lo + 64))
                   ? ~0ull
                   : ((nvalid > (unsigned)lo) ? ((1ull << (nvalid - lo)) - 1ull) : 0ull);
  }

  // ---- (5) scan loop: scalar ffs -> uniform box read -> per-lane IoU ballots ----
  for (int it = 0; it < MAXDET; ++it) {
    int r = -1;
#pragma unroll
    for (int w = 15; w >= 0; --w)
      if (alive[w]) r = w * 64 + __builtin_ctzll(alive[w]);
    if (r < 0) break;  // uniform; wins[] stays sentinel
    if (lane == 0) wins[it] = (unsigned)r;  // fire-and-forget
    float4 B = boxe[r];                     // ONE uniform ds_read_b128
    float areaB = (B.z - B.x) * (B.w - B.y);
#pragma unroll
    for (int k = 0; k < 16; ++k) {
      int c = k * 64 + lane;
      float lx = fmaxf(B.x, x1o[k]), ly = fmaxf(B.y, y1o[k]);
      float rx = fminf(B.z, x2o[k]), ry = fminf(B.w, y2o[k]);
      float iw = fmaxf(rx - lx, 0.f), ih = fmaxf(ry - ly, 0.f);
      float inter = iw * ih;
      float uu = areaB + area[k] - inter;
      float ss = fmaf(2.0f, inter, -uu);  // exact 2i-u in the decision region (Sterbenz)
      float tt = uu * 0x1p-24f;           // exact scale; RN(i/u)>0.5 <=> ss>tt
      bool sup = (uu > 0.f && ss > tt) || (c == r);
      alive[k] &= ~__ballot(sup);
    }
  }
  __syncthreads();

  // ---- epilogue: gather winner payloads (rank -> slot via key64), flush ----
  for (int t = lane; t < MAXDET; t += 64) {
    unsigned r = wins[t];
    float* row = lout + t * 7;
    if (r == 0xFFFFFFFFu) {
      row[0] = 0.f; row[1] = 0.f; row[2] = 0.f; row[3] = 0.f;
      row[4] = 0.f; row[5] = 0.f; row[6] = 0.f;
    } else {
      unsigned slot = (unsigned)(key64[r] & 1023ull);
      float4 p0 = pay0[slot];
      float4 p1 = pay1[slot];
      row[0] = p0.x; row[1] = p0.y; row[2] = p0.z; row[3] = p0.w;
      row[4] = p1.x; row[5] = p1.y; row[6] = p1.z;
    }
  }
  __syncthreads();
  float4* go4 = reinterpret_cast<float4*>(out + (size_t)img * MAXDET * 7);
  for (int p = lane; p < MAXDET * 7 / 4; p += 64) go4[p] = lout4[p];
}

// ---------------- launch ----------------
extern "C" void kernel_launch(void* const* d_in, const int* in_sizes, int n_in,
                              void* d_out, int out_size, void* d_ws, size_t ws_size,
                              hipStream_t stream) {
  const float* regs = (const float*)d_in[0];
  const float* clses = (const float*)d_in[1];
  const float* anchors = (const float*)d_in[2];
  float* out = (float*)d_out;
  char* ws = (char*)d_ws;

  constexpr size_t HIST_BYTES = (size_t)BB * 65536 * 4;  // 4 MiB
  constexpr size_t META_OFF = HIST_BYTES;
  constexpr size_t META_BYTES = 1024;
  constexpr size_t KEYS_OFF = META_OFF + META_BYTES;
  constexpr size_t ARR_BYTES = (size_t)BB * NN * 4;
  constexpr size_t CCS_OFF = KEYS_OFF + ARR_BYTES;
  constexpr size_t PREDS_OFF = CCS_OFF + ARR_BYTES;
  constexpr size_t CAND_OFF = PREDS_OFF + ARR_BYTES;
  constexpr size_t CAND_BYTES = (size_t)10 * BB * CAND_CAP * 4;
  constexpr size_t TIES_OFF = CAND_OFF + CAND_BYTES;

  unsigned* hist1 = (unsigned*)(ws);
  Meta* meta = (Meta*)(ws + META_OFF);
  unsigned* keys = (unsigned*)(ws + KEYS_OFF);
  float* ccs = (float*)(ws + CCS_OFF);
  int* preds = (int*)(ws + PREDS_OFF);
  float* cand = (float*)(ws + CAND_OFF);
  unsigned long long* ties = (unsigned long long*)(ws + TIES_OFF);

  // zero hist1 + meta every launch (ws is not re-poisoned between replays)
  hipMemsetAsync(d_ws, 0, KEYS_OFF, stream);

  k_score<<<BB * BPI_S, 256, 0, stream>>>(regs, clses, keys, ccs, preds, hist1);
  k_scan<<<BB, 256, 0, stream>>>(hist1, meta);
  k_compact<<<BB * BPI_C, 256, 0, stream>>>(regs, anchors, keys, ccs, preds, meta, cand, ties);
  k_nms<<<BB, 64, 0, stream>>>(cand, meta, out, regs, anchors, ccs, preds, ties);
}

// Round 11
// 187.244 us; speedup vs baseline: 1.5475x; 1.5475x over previous
//
#include <hip/hip_runtime.h>
#include <math.h>

#define BB 16
#define NN 25200
#define NCLS 80
#define TOPK 1000
#define MAXDET 100
#define CAND_CAP 2048
#define RANKS 1024
#define HBINS 1024
#define HBASE 0xBD00u
#define BPI_S 394   // blocks/img for k_score: ceil(25200*4/256)
#define BPI_C 99    // blocks/img for k_compact: ceil(25200/256)
static constexpr float NEGV = -1000000000.0f;
static constexpr float IMGSZ = 640.0f;

struct Meta {
  unsigned b1;      // absolute k16 of cutoff bin
  unsigned n_true;  // min(TOPK, #keys with k16 >= b1)  == reference candidate count
  unsigned cnt;     // k_compact atomic counter (#loaded candidates)
  unsigned pad;
};

__device__ __forceinline__ unsigned flipKey(float f) {
  unsigned u = __float_as_uint(f);
  return (u & 0x80000000u) ? ~u : (u | 0x80000000u);
}
__device__ __forceinline__ float unflipKey(unsigned k) {
  unsigned u = (k & 0x80000000u) ? (k & 0x7FFFFFFFu) : ~k;
  return __uint_as_float(u);
}

#define UMAX_DPP(VAR, CTRL)                                                                   \
  {                                                                                           \
    unsigned _o = (unsigned)__builtin_amdgcn_update_dpp(0, (int)(VAR), CTRL, 0xF, 0xF, true); \
    if (_o > (VAR)) (VAR) = _o;                                                               \
  }

// ---------------- phase 1: scores + 1024-bin histogram (4 lanes per row) ----------------
__global__ void __launch_bounds__(256) k_score(const float* __restrict__ regs,
                                               const float* __restrict__ clses,
                                               unsigned* __restrict__ keys,
                                               float* __restrict__ ccs,
                                               int* __restrict__ preds,
                                               unsigned* __restrict__ hist1) {
  int img = blockIdx.x / BPI_S;
  int t = (blockIdx.x % BPI_S) * 256 + threadIdx.x;
  int rl = t >> 2, q = t & 3;
  if (rl >= NN) return;
  size_t row = (size_t)img * NN + (size_t)rl;
  const float4* r4 = reinterpret_cast<const float4*>(clses + row * NCLS);
  float best = -1.0f;
  int bi = 0;
#pragma unroll
  for (int u = 0; u < 5; ++u) {
    float4 v = r4[q + 4 * u];
    int b0 = (q + 4 * u) * 4;
    if (v.x > best) { best = v.x; bi = b0 + 0; }
    if (v.y > best) { best = v.y; bi = b0 + 1; }
    if (v.z > best) { best = v.z; bi = b0 + 2; }
    if (v.w > best) { best = v.w; bi = b0 + 3; }
  }
  unsigned vb = __float_as_uint(best);
  unsigned m = vb;
  UMAX_DPP(m, 0xB1);  // quad_perm [1,0,3,2]
  UMAX_DPP(m, 0x4E);  // quad_perm [2,3,0,1]
  unsigned t2 = (vb == m) ? (unsigned)(79 - bi) : 0u;
  UMAX_DPP(t2, 0xB1);
  UMAX_DPP(t2, 0x4E);
  if (q == 0) {
    float bestv = __uint_as_float(m);
    int bidx = 79 - (int)t2;
    float pobj = regs[row * 5 + 4];
    float sc = pobj * bestv;
    float s = (sc >= 0.05f) ? sc : NEGV;
    unsigned key = flipKey(s);
    keys[row] = key;
    ccs[row] = bestv;
    preds[row] = bidx;
    int b = (int)(key >> 16) - (int)HBASE;  // scores<=1 -> k16<=0xBF80 -> b<=0x280
    unsigned bin = (b < 1) ? 0u : (unsigned)b;
    atomicAdd(&hist1[(size_t)img * HBINS + bin], 1u);
  }
}

// ---------------- histogram scan: cutoff bin + n_true ----------------
__global__ void __launch_bounds__(256) k_scan(const unsigned* __restrict__ hist,
                                              Meta* __restrict__ meta) {
  __shared__ unsigned part[256];
  __shared__ unsigned sfx[256];
  __shared__ int s_sel;
  __shared__ unsigned s_cum;
  int img = blockIdx.x;
  int t = threadIdx.x;
  const unsigned* h = hist + (size_t)img * HBINS;
  uint4 mine = reinterpret_cast<const uint4*>(h)[t];  // bins 4t..4t+3
  unsigned s = mine.x + mine.y + mine.z + mine.w;
  if (t == 0) { s_sel = 0; s_cum = 0; }
  part[t] = s;
  sfx[t] = s;
  __syncthreads();
  for (int d = 1; d < 256; d <<= 1) {
    unsigned v = (t + d < 256) ? sfx[t + d] : 0u;
    __syncthreads();
    sfx[t] += v;
    __syncthreads();
  }
  {
    unsigned incl = sfx[t];
    unsigned excl = incl - part[t];
    if (incl >= (unsigned)TOPK && excl < (unsigned)TOPK) { s_sel = t; s_cum = excl; }
  }
  __syncthreads();
  if (t == s_sel) {
    unsigned cum = s_cum;  // count in bins above this chunk
    unsigned vals[4] = {mine.x, mine.y, mine.z, mine.w};
    int sel = 0;
    unsigned c_ge = 0;
    for (int j = 3; j >= 0; --j) {  // high bin -> low bin
      if (cum + vals[j] >= (unsigned)TOPK) { sel = j; c_ge = cum + vals[j]; break; }
      cum += vals[j];
    }
    meta[img].b1 = HBASE + (unsigned)(4 * t + sel);
    meta[img].n_true = (c_ge > (unsigned)TOPK) ? (unsigned)TOPK : c_ge;
  }
}

// ---------------- compaction: ALL candidates with k16 >= b1 (no tie machinery) ----------
__global__ void k_compact(const float* __restrict__ regs, const float* __restrict__ anchors,
                          const unsigned* __restrict__ keys, const float* __restrict__ ccs,
                          const int* __restrict__ preds, Meta* __restrict__ meta,
                          float* __restrict__ cand) {
  const size_t S2 = (size_t)BB * CAND_CAP;
  int img = blockIdx.x / BPI_C;
  int i = (blockIdx.x % BPI_C) * 256 + threadIdx.x;
  if (i >= NN) return;
  int lane = threadIdx.x & 63;
  unsigned long long lt = (1ull << lane) - 1ull;
  size_t g = (size_t)img * NN + (size_t)i;
  unsigned key = keys[g];
  bool take = (key >> 16) >= meta[img].b1;
  unsigned long long mA = __ballot(take);
  if (!take) return;
  int leader = __builtin_ctzll(mA);
  unsigned base = 0;
  if (lane == leader) base = atomicAdd(&meta[img].cnt, (unsigned)__popcll(mA));
  base = __shfl(base, leader);
  unsigned pos = base + (unsigned)__popcll(mA & lt);
  if (pos >= CAND_CAP) return;
  const float* r = regs + g * 5;
  float d0 = r[0], d1 = r[1], d2 = r[2], d3 = r[3], obj = r[4];
  const float* a = anchors + (size_t)i * 4;
  float ax1 = a[0], ay1 = a[1], ax2 = a[2], ay2 = a[3];
  float aw = ax2 - ax1, ah = ay2 - ay1;
  float acx = (ax1 + ax2) * 0.5f, acy = (ay1 + ay2) * 0.5f;
  float cx = acx + d0 * aw, cy = acy + d1 * ah;
  float w = aw * expf(d2), h = ah * expf(d3);
  float hw = 0.5f * w, hh = 0.5f * h;
  float x1 = fminf(fmaxf(cx - hw, 0.0f), IMGSZ);
  float y1 = fminf(fmaxf(cy - hh, 0.0f), IMGSZ);
  float x2 = fminf(fmaxf(cx + hw, 0.0f), IMGSZ);
  float y2 = fminf(fmaxf(cy + hh, 0.0f), IMGSZ);
  size_t o = (size_t)img * CAND_CAP + pos;
  cand[0 * S2 + o] = x1;
  cand[1 * S2 + o] = y1;
  cand[2 * S2 + o] = x2;
  cand[3 * S2 + o] = y2;
  cand[4 * S2 + o] = obj;
  cand[5 * S2 + o] = ccs[g];
  cand[6 * S2 + o] = (float)preds[g];
  cand[7 * S2 + o] = unflipKey(key);
  reinterpret_cast<unsigned*>(cand + 8 * S2)[o] = (unsigned)i;
}

// ---------------- rank by counting: rank = #bigger 48-bit keys; scatter to rank space ----
// Grid 16 img x 32 parts; 4 threads per slot each count 512 keys; quad-DPP sum.
// True top-n_true candidates land at ranks 0..n_true-1 (exact reference top-k set);
// extras (same-bin, lower key) get ranks >= n_true and are never alive in the scan.
__global__ void __launch_bounds__(256) k_rank(const float* __restrict__ cand,
                                              const Meta* __restrict__ meta,
                                              float* __restrict__ boxr,
                                              float4* __restrict__ payr0,
                                              float4* __restrict__ payr1) {
  const size_t S2 = (size_t)BB * CAND_CAP;
  const int NR = BB * RANKS;
  __shared__ unsigned long long kk[CAND_CAP];  // 16 KB
  int img = blockIdx.x >> 5;
  int part = blockIdx.x & 31;
  int tid = threadIdx.x;
  unsigned nload = meta[img].cnt;
  if (nload > CAND_CAP) nload = CAND_CAP;
  for (int i = tid; i < CAND_CAP; i += 256) {
    unsigned long long kv = 0ull;
    if (i < (int)nload) {
      float sc = cand[7 * S2 + (size_t)img * CAND_CAP + i];
      unsigned ai = reinterpret_cast<const unsigned*>(cand + 8 * S2)[(size_t)img * CAND_CAP + i];
      kv = ((unsigned long long)flipKey(sc) << 16) |
           (unsigned long long)((0x7FFFu - ai) & 0xFFFFu);  // unique via ai
    }
    kk[i] = kv;
  }
  __syncthreads();
  int slot = part * 64 + (tid >> 2);
  int qtr = tid & 3;
  unsigned long long myk = kk[slot];
  unsigned rank = 0;
  for (int q = qtr * 512; q < qtr * 512 + 512; ++q) rank += (kk[q] > myk) ? 1u : 0u;
  rank += (unsigned)__builtin_amdgcn_update_dpp(0, (int)rank, 0xB1, 0xF, 0xF, true);
  rank += (unsigned)__builtin_amdgcn_update_dpp(0, (int)rank, 0x4E, 0xF, 0xF, true);
  if (qtr == 0 && slot < (int)nload && rank < RANKS) {
    size_t o = (size_t)img * CAND_CAP + slot;
    float x1 = cand[0 * S2 + o], y1 = cand[1 * S2 + o];
    float x2 = cand[2 * S2 + o], y2 = cand[3 * S2 + o];
    float obj = cand[4 * S2 + o], cc = cand[5 * S2 + o];
    float cp = cand[6 * S2 + o], sc = cand[7 * S2 + o];
    float offv = cp * 4096.0f;
    float a1 = x1 + offv, b1v = y1 + offv, a2 = x2 + offv, b2v = y2 + offv;
    size_t ro = (size_t)img * RANKS + rank;
    boxr[0 * NR + ro] = a1;
    boxr[1 * NR + ro] = b1v;
    boxr[2 * NR + ro] = a2;
    boxr[3 * NR + ro] = b2v;
    boxr[4 * NR + ro] = (a2 - a1) * (b2v - b1v);
    payr0[ro] = make_float4(x1, y1, x2, y2);
    payr1[ro] = make_float4(obj, cc, cp, sc);
  }
}

// ---------------- suppression bit-matrix in rank space (parallel) ----------------
// mat[img][r] = 1024-bit row: bit c set iff RN(IoU(r,c)) > 0.5 (division-free exact) or c==r.
__global__ void __launch_bounds__(256) k_matrix(const float* __restrict__ boxr,
                                                const Meta* __restrict__ meta,
                                                unsigned long long* __restrict__ mat) {
  const int NR = BB * RANKS;
  __shared__ float sx1[RANKS], sy1[RANKS], sx2[RANKS], sy2[RANKS], sar[RANKS];  // 20 KB
  int img = blockIdx.x >> 6;
  int part = blockIdx.x & 63;
  int tid = threadIdx.x, lane = tid & 63, wid = tid >> 6;
  for (int i = tid; i < RANKS; i += 256) {
    int g = img * RANKS + i;
    sx1[i] = boxr[0 * NR + g];
    sy1[i] = boxr[1 * NR + g];
    sx2[i] = boxr[2 * NR + g];
    sy2[i] = boxr[3 * NR + g];
    sar[i] = boxr[4 * NR + g];
  }
  unsigned n = meta[img].n_true;
  __syncthreads();
#pragma unroll
  for (int rr = 0; rr < 4; ++rr) {
    int r = part * 16 + wid * 4 + rr;
    if (r >= (int)n) continue;  // wave-uniform
    float bx1 = sx1[r], by1 = sy1[r], bx2 = sx2[r], by2 = sy2[r], bA = sar[r];
    unsigned long long* rowp = mat + ((size_t)img * RANKS + r) * 16;
#pragma unroll
    for (int w2 = 0; w2 < 16; ++w2) {
      int c = w2 * 64 + lane;
      float lx = fmaxf(bx1, sx1[c]), ly = fmaxf(by1, sy1[c]);
      float rx = fminf(bx2, sx2[c]), ry = fminf(by2, sy2[c]);
      float iw = fmaxf(rx - lx, 0.f), ih = fmaxf(ry - ly, 0.f);
      float inter = iw * ih;
      float uu = bA + sar[c] - inter;
      float ss = fmaf(2.0f, inter, -uu);  // exact 2i-u (Sterbenz in decision region)
      float tt = uu * 0x1p-24f;           // RN(i/u)>0.5 <=> ss>tt
      bool sup = (uu > 0.f && ss > tt) || (c == r);
      unsigned long long b = __ballot(sup);
      if (lane == w2) rowp[w2] = b;
    }
  }
}

// ---------------- serial scan: trivial chain (ballot + shfl + one LDS row read) --------
__global__ void __launch_bounds__(256, 1) k_scan2(const unsigned long long* __restrict__ mat,
                                                  const Meta* __restrict__ meta,
                                                  const float4* __restrict__ payr0,
                                                  const float4* __restrict__ payr1,
                                                  float* __restrict__ out) {
  __shared__ unsigned long long smat[RANKS * 16];  // 128 KB
  __shared__ unsigned wins[MAXDET];
  __shared__ float4 lout4[MAXDET * 7 / 4];
  int img = blockIdx.x, tid = threadIdx.x, lane = tid & 63, wid = tid >> 6;
  const uint4* gm = reinterpret_cast<const uint4*>(mat + (size_t)img * RANKS * 16);
  uint4* sm4 = reinterpret_cast<uint4*>(smat);
  for (int i = tid; i < RANKS * 16 / 2; i += 256) sm4[i] = gm[i];
  if (tid < MAXDET) wins[tid] = 0xFFFFFFFFu;
  unsigned n = meta[img].n_true;
  __syncthreads();
  if (wid == 0) {
    unsigned long long alive = 0ull;
    if (lane < 16) {
      int lo = lane * 64;
      alive = ((int)n >= lo + 64) ? ~0ull
                                  : (((int)n > lo) ? ((1ull << ((int)n - lo)) - 1ull) : 0ull);
    }
    for (int it = 0; it < MAXDET; ++it) {
      unsigned long long any = __ballot(alive != 0ull);
      if (any == 0ull) break;  // rest of rows zero via sentinel
      int f = __builtin_ctzll(any);
      unsigned long long w = __shfl(alive, f);
      int r = f * 64 + __builtin_ctzll(w);
      if (lane == 0) wins[it] = (unsigned)r;
      unsigned long long rowv = (lane < 16) ? smat[r * 16 + lane] : 0ull;
      alive &= ~rowv;  // diag bit clears the winner itself
    }
  }
  __syncthreads();
  if (tid < MAXDET) {
    unsigned r = wins[tid];
    float* row = reinterpret_cast<float*>(lout4) + tid * 7;
    if (r == 0xFFFFFFFFu) {
      row[0] = 0.f; row[1] = 0.f; row[2] = 0.f; row[3] = 0.f;
      row[4] = 0.f; row[5] = 0.f; row[6] = 0.f;
    } else {
      float4 p0 = payr0[(size_t)img * RANKS + r];
      float4 p1 = payr1[(size_t)img * RANKS + r];
      row[0] = p0.x; row[1] = p0.y; row[2] = p0.z; row[3] = p0.w;
      row[4] = p1.x; row[5] = p1.y; row[6] = p1.z;
    }
  }
  __syncthreads();
  float4* go4 = reinterpret_cast<float4*>(out + (size_t)img * MAXDET * 7);
  if (tid < MAXDET * 7 / 4) go4[tid] = lout4[tid];
}

// ---------------- launch ----------------
extern "C" void kernel_launch(void* const* d_in, const int* in_sizes, int n_in,
                              void* d_out, int out_size, void* d_ws, size_t ws_size,
                              hipStream_t stream) {
  const float* regs = (const float*)d_in[0];
  const float* clses = (const float*)d_in[1];
  const float* anchors = (const float*)d_in[2];
  float* out = (float*)d_out;
  char* ws = (char*)d_ws;

  constexpr size_t HIST_BYTES = (size_t)BB * HBINS * 4;  // 64 KB
  constexpr size_t META_OFF = HIST_BYTES;
  constexpr size_t META_BYTES = 1024;
  constexpr size_t KEYS_OFF = META_OFF + META_BYTES;
  constexpr size_t ARR_BYTES = (size_t)BB * NN * 4;
  constexpr size_t CCS_OFF = KEYS_OFF + ARR_BYTES;
  constexpr size_t PREDS_OFF = CCS_OFF + ARR_BYTES;
  constexpr size_t CAND_OFF = PREDS_OFF + ARR_BYTES;
  constexpr size_t CAND_BYTES = (size_t)9 * BB * CAND_CAP * 4;  // 1.18 MB
  constexpr size_t BOXR_OFF = CAND_OFF + CAND_BYTES;
  constexpr size_t BOXR_BYTES = (size_t)5 * BB * RANKS * 4;  // 320 KB
  constexpr size_t PAYR_OFF = BOXR_OFF + BOXR_BYTES;
  constexpr size_t PAYR_BYTES = (size_t)2 * BB * RANKS * 16;  // 512 KB
  constexpr size_t MAT_OFF = PAYR_OFF + PAYR_BYTES;
  // MAT: BB * RANKS * 16 u64 = 2 MB

  unsigned* hist1 = (unsigned*)(ws);
  Meta* meta = (Meta*)(ws + META_OFF);
  unsigned* keys = (unsigned*)(ws + KEYS_OFF);
  float* ccs = (float*)(ws + CCS_OFF);
  int* preds = (int*)(ws + PREDS_OFF);
  float* cand = (float*)(ws + CAND_OFF);
  float* boxr = (float*)(ws + BOXR_OFF);
  float4* payr0 = (float4*)(ws + PAYR_OFF);
  float4* payr1 = (float4*)(ws + PAYR_OFF + (size_t)BB * RANKS * 16);
  unsigned long long* mat = (unsigned long long*)(ws + MAT_OFF);

  // zero hist + meta every launch (ws is not re-poisoned between replays)
  hipMemsetAsync(d_ws, 0, KEYS_OFF, stream);

  k_score<<<BB * BPI_S, 256, 0, stream>>>(regs, clses, keys, ccs, preds, hist1);
  k_scan<<<BB, 256, 0, stream>>>(hist1, meta);
  k_compact<<<BB * BPI_C, 256, 0, stream>>>(regs, anchors, keys, ccs, preds, meta, cand);
  k_rank<<<BB * 32, 256, 0, stream>>>(cand, meta, boxr, payr0, payr1);
  k_matrix<<<BB * 64, 256, 0, stream>>>(boxr, meta, mat);
  k_scan2<<<BB, 256, 0, stream>>>(mat, meta, payr0, payr1, out);
}